// Round 12
// baseline (752.114 us; speedup 1.0000x reference)
//
#include <hip/hip_runtime.h>

#define N_NODES 50000
#define N_ENT   100000
#define N_REL   16
#define DIM     128
#define E_EDGES 600000
#define NQ      8192
#define PATH_DIM 5
#define NK      (N_NODES * N_REL)        /* 800000 (rel,dst) segments, rel-major */
#define NBLK_SEG (NK / 256)              /* 3125 */
#define KTOT    (N_REL * DIM + DIM)      /* 2176 */
#define NG      (KTOT / 32)              /* 68 */
#define BM      64                       /* rows per block (4 waves x 16) */
#define EB      ((E_EDGES + 255) / 256)
#define H0B     ((N_NODES * 32) / 256)
#define WCB     ((2 * NG * 8 * 512) / 256)

typedef __attribute__((ext_vector_type(8))) short short8;
typedef __attribute__((ext_vector_type(4))) float floatx4;
typedef __attribute__((ext_vector_type(4))) unsigned uintx4;

static __device__ __forceinline__ short f2bf(float x) {
  unsigned u = __builtin_bit_cast(unsigned, x);
  u = (u + 0x7FFFu + ((u >> 16) & 1u)) >> 16;   // RNE
  return (short)u;
}
static __device__ __forceinline__ float bf_lo(unsigned u) {
  return __builtin_bit_cast(float, u << 16);
}
static __device__ __forceinline__ float bf_hi(unsigned u) {
  return __builtin_bit_cast(float, u & 0xffff0000u);
}
static __device__ __forceinline__ unsigned pk2(float a, float b) {
  return (unsigned)(unsigned short)f2bf(a) | ((unsigned)(unsigned short)f2bf(b) << 16);
}

static __device__ __forceinline__ int wave_incl_scan(int x) {
  int lane = threadIdx.x & 63;
  #pragma unroll
  for (int off = 1; off < 64; off <<= 1) {
    int y = __shfl_up(x, off, 64);
    if (lane >= off) x += y;
  }
  return x;
}

// ---------- fused prep: edge hist | h0 gather | weight tiles ----------
__global__ void k_prep(const int* __restrict__ ei, const int* __restrict__ et,
                       int* __restrict__ hist,
                       const int* __restrict__ nid, const float* __restrict__ emb,
                       unsigned* __restrict__ h,
                       const float* __restrict__ wrel, const float* __restrict__ wself,
                       short* __restrict__ wt) {
  int b = blockIdx.x, t = threadIdx.x;
  if (b < EB) {
    int e = b * 256 + t;
    if (e < E_EDGES) {
      int key = et[e] * N_NODES + ei[E_EDGES + e];
      atomicAdd(&hist[key], 1);
    }
  } else if (b < EB + H0B) {
    int g = (b - EB) * 256 + t;                    // over N*32
    int n = g >> 5, q = g & 31;
    float4 v = *(const float4*)(emb + (size_t)nid[n] * DIM + q * 4);
    uint2 pk;
    pk.x = pk2(v.x, v.y);
    pk.y = pk2(v.z, v.w);
    *(uint2*)(h + (size_t)n * 64 + q * 2) = pk;
  } else {
    // wt layout: [l][g=k/32][nt8=n/16] tile [16 rA][32 q] shorts (1KB)
    int idx = (b - EB - H0B) * 256 + t;
    int within = idx & 511;
    int tile = idx >> 9;
    int rA = within >> 5, q = within & 31;
    int nt8 = tile & 7;
    int lg = tile >> 3;
    int l = lg / NG, g = lg % NG;
    int n = nt8 * 16 + rA;
    int k = g * 32 + q;
    float v;
    if (k < N_REL * DIM) {
      int r = k >> 7, d = k & 127;
      v = wrel[(((size_t)l * N_REL + r) * DIM + d) * DIM + n];
    } else {
      int d = k - N_REL * DIM;
      v = wself[((size_t)l * DIM + d) * DIM + n];
    }
    wt[idx] = f2bf(v);
  }
}

__global__ void k_bsum(const int* __restrict__ hist, int* __restrict__ bsum) {
  int t = threadIdx.x;
  int v = hist[blockIdx.x * 256 + t];
  #pragma unroll
  for (int off = 32; off; off >>= 1) v += __shfl_xor(v, off, 64);
  __shared__ int s4[4];
  if ((t & 63) == 0) s4[t >> 6] = v;
  __syncthreads();
  if (t == 0) bsum[blockIdx.x] = s4[0] + s4[1] + s4[2] + s4[3];
}

__global__ void k_bscan(int* __restrict__ bsum) {   // 1 block, 1024 threads
  int t = threadIdx.x;
  int v[4], loc[4], s = 0;
  #pragma unroll
  for (int i = 0; i < 4; i++) {
    int idx = t * 4 + i;
    v[i] = (idx < NBLK_SEG) ? bsum[idx] : 0;
    loc[i] = s; s += v[i];
  }
  int incl = wave_incl_scan(s);
  __shared__ int wsum[16];
  int wid = t >> 6, lane = t & 63;
  if (lane == 63) wsum[wid] = incl;
  __syncthreads();
  if (t < 16) {
    int x = wsum[t];
    #pragma unroll
    for (int off = 1; off < 16; off <<= 1) {
      int y = __shfl_up(x, off, 64);
      if (t >= off) x += y;
    }
    wsum[t] = x;
  }
  __syncthreads();
  int wexcl = wid ? wsum[wid - 1] : 0;
  int texcl = wexcl + incl - s;
  #pragma unroll
  for (int i = 0; i < 4; i++) {
    int idx = t * 4 + i;
    if (idx < NBLK_SEG) bsum[idx] = texcl + loc[i];
  }
}

__global__ void k_offsets(const int* __restrict__ hist, const int* __restrict__ bsum,
                          int* __restrict__ offs, int* __restrict__ cursor) {
  int t = threadIdx.x;
  int g = blockIdx.x * 256 + t;
  int v = hist[g];
  int incl = wave_incl_scan(v);
  __shared__ int wsum[4];
  int wid = t >> 6, lane = t & 63;
  if (lane == 63) wsum[wid] = incl;
  __syncthreads();
  int wexcl = 0;
  for (int i = 0; i < wid; i++) wexcl += wsum[i];
  int off = bsum[blockIdx.x] + wexcl + incl - v;
  offs[g] = off;
  cursor[g] = off;
  if (g == NK - 1) offs[NK] = off + v;
}

__global__ void k_scatter(const int* __restrict__ ei, const int* __restrict__ et,
                          int* __restrict__ cursor, int* __restrict__ ssrc) {
  int e = blockIdx.x * 256 + threadIdx.x;
  if (e >= E_EDGES) return;
  int src = ei[e];
  int key = et[e] * N_NODES + ei[E_EDGES + e];
  int pos = atomicAdd(&cursor[key], 1);
  ssrc[pos] = src;
}

// ---------- fused layer: per-lane segments, paired relations, shfl-distributed ids ----
// Wave owns 16 rows; lane=(row rA, chans quad*8+ks*32..+7). Per relation the wave's
// 16 segments are one contiguous ssrc range (<=64 essentially always): ONE coalesced
// load grabs all edge ids; the inner loop gets ids via ds_bpermute (no memory chain).
// Two relations iterate together: both load streams in flight before either is
// consumed -> one latency-wait serves two relations. No K-loop barriers.
__global__ __launch_bounds__(256, 3)
void k_layer(const unsigned* __restrict__ hin, const int* __restrict__ offs,
             const int* __restrict__ ssrc, const short* __restrict__ wt,
             unsigned* __restrict__ hout) {
  __shared__ int offsS[16][66];       // per-rel segment boundaries for block rows
  int t = threadIdx.x;
  int w = t >> 6, lane = t & 63;
  int quad = lane >> 4, rA = lane & 15;
  int w16 = w * 16;
  int row0 = blockIdx.x * BM;

  for (int idx = t; idx < 16 * 80; idx += 256) {
    int r = idx / 80, j = idx - r * 80;
    if (j < 65) offsS[r][j] = offs[min(r * N_NODES + row0 + j, NK)];
  }
  __syncthreads();                    // the only block barrier

  floatx4 acc[8];
  #pragma unroll
  for (int nt = 0; nt < 8; ++nt) acc[nt] = (floatx4)0.f;

  const short* hb = (const short*)hin;

  // per-relation segment state (A = even rel of pair, B = odd)
  int oA, cA, idvA, baseA, oB, cB, idvB, baseB;
  bool fastA, fastB;
  auto load_rel = [&](int r, int &o, int &c, int &idv, int &base, bool &fast) {
    o = offsS[r][w16 + rA];
    c = offsS[r][w16 + rA + 1] - o;
    int o0w = offsS[r][w16];
    int tot = offsS[r][w16 + 16] - o0w;
    fast = (tot <= 64);
    base = o - o0w;
    idv = ssrc[min(o0w + lane, E_EDGES - 1)];   // one coalesced wave load
  };
  auto finish_rel = [&](float (&s)[4][8], int c, int r) {
    float inv = 1.0f / (float)(c > 0 ? c : 1);  // lane-local
    short8 af[4];
    #pragma unroll
    for (int ks = 0; ks < 4; ++ks) {
      uintx4 ap;
      #pragma unroll
      for (int m = 0; m < 4; ++m) {
        float a = s[ks][2 * m] * inv, b = s[ks][2 * m + 1] * inv;
        unsigned pk;
        asm("v_cvt_pk_bf16_f32 %0, %1, %2" : "=v"(pk) : "v"(a), "v"(b));  // RNE
        ap[m] = pk;
      }
      af[ks] = __builtin_bit_cast(short8, ap);
    }
    #pragma unroll
    for (int ks = 0; ks < 4; ++ks) {
      const short* bp = wt + (size_t)((r * 4 + ks) * 8) * 512 + rA * 32 + quad * 8;
      #pragma unroll
      for (int nt = 0; nt < 8; ++nt) {
        short8 b = *(const short8*)(bp + nt * 512);   // 1KB tile, L2-hot
        acc[nt] = __builtin_amdgcn_mfma_f32_16x16x32_bf16(af[ks], b, acc[nt], 0, 0, 0);
      }
    }
  };

  load_rel(0, oA, cA, idvA, baseA, fastA);
  load_rel(1, oB, cB, idvB, baseB, fastB);

  for (int rp = 0; rp < 16; rp += 2) {
    float sA[4][8], sB[4][8];
    #pragma unroll
    for (int ks = 0; ks < 4; ++ks)
      #pragma unroll
      for (int m = 0; m < 8; ++m) { sA[ks][m] = 0.f; sB[ks][m] = 0.f; }

    int mm = max(cA, cB);
    #pragma unroll
    for (int sh = 32; sh; sh >>= 1) mm = max(mm, __shfl_xor(mm, sh, 64));

    for (int i = 0; i < mm; ++i) {
      int eA, eB;
      if (fastA) eA = __shfl(idvA, min(baseA + i, 63), 64);   // ds_bpermute, no mem
      else       eA = (i < cA) ? ssrc[oA + i] : 0;            // rare fallback
      if (fastB) eB = __shfl(idvB, min(baseB + i, 63), 64);
      else       eB = (i < cB) ? ssrc[oB + i] : 0;
      bool pA = i < cA, pB = i < cB;
      uint4 dA[4], dB[4];
      if (pA) {
        const short* hp = hb + (size_t)eA * DIM + quad * 8;
        #pragma unroll
        for (int ks = 0; ks < 4; ++ks) dA[ks] = *(const uint4*)(hp + ks * 32);
      }
      if (pB) {
        const short* hp = hb + (size_t)eB * DIM + quad * 8;
        #pragma unroll
        for (int ks = 0; ks < 4; ++ks) dB[ks] = *(const uint4*)(hp + ks * 32);
      }
      __builtin_amdgcn_sched_barrier(0);       // both streams issued before consumes
      if (pA) {
        #pragma unroll
        for (int ks = 0; ks < 4; ++ks) {
          uint4 d = dA[ks];
          sA[ks][0] += bf_lo(d.x); sA[ks][1] += bf_hi(d.x);
          sA[ks][2] += bf_lo(d.y); sA[ks][3] += bf_hi(d.y);
          sA[ks][4] += bf_lo(d.z); sA[ks][5] += bf_hi(d.z);
          sA[ks][6] += bf_lo(d.w); sA[ks][7] += bf_hi(d.w);
        }
      }
      if (pB) {
        #pragma unroll
        for (int ks = 0; ks < 4; ++ks) {
          uint4 d = dB[ks];
          sB[ks][0] += bf_lo(d.x); sB[ks][1] += bf_hi(d.x);
          sB[ks][2] += bf_lo(d.y); sB[ks][3] += bf_hi(d.y);
          sB[ks][4] += bf_lo(d.z); sB[ks][5] += bf_hi(d.z);
          sB[ks][6] += bf_lo(d.w); sB[ks][7] += bf_hi(d.w);
        }
      }
    }

    // prefetch next pair's state; its id-vector loads hide under the MFMAs below
    int oA2 = 0, cA2 = 0, idvA2 = 0, baseA2 = 0, oB2 = 0, cB2 = 0, idvB2 = 0, baseB2 = 0;
    bool fastA2 = true, fastB2 = true;
    if (rp + 2 < 16) {
      load_rel(rp + 2, oA2, cA2, idvA2, baseA2, fastA2);
      load_rel(rp + 3, oB2, cB2, idvB2, baseB2, fastB2);
    }
    int cAh = cA, cBh = cB;           // finish uses pre-rotation counts
    finish_rel(sA, cAh, rp);
    finish_rel(sB, cBh, rp + 1);
    oA = oA2; cA = cA2; idvA = idvA2; baseA = baseA2; fastA = fastA2;
    oB = oB2; cB = cB2; idvB = idvB2; baseB = baseB2; fastB = fastB2;
  }

  // self slot: A-frag = raw bf16 slices of own h row
  {
    int lr = min(row0 + w16 + rA, N_NODES - 1);
    const short* hp = hb + (size_t)lr * DIM + quad * 8;
    #pragma unroll
    for (int ks = 0; ks < 4; ++ks) {
      short8 af = *(const short8*)(hp + ks * 32);
      const short* bp = wt + (size_t)((16 * 4 + ks) * 8) * 512 + rA * 32 + quad * 8;
      #pragma unroll
      for (int nt = 0; nt < 8; ++nt) {
        short8 b = *(const short8*)(bp + nt * 512);
        acc[nt] = __builtin_amdgcn_mfma_f32_16x16x32_bf16(af, b, acc[nt], 0, 0, 0);
      }
    }
  }

  // epilogue: C row=quad*4+j, col=nt*16+rA
  #pragma unroll
  for (int nt = 0; nt < 8; ++nt)
    #pragma unroll
    for (int j = 0; j < 4; ++j) {
      int row = row0 + w16 + quad * 4 + j;
      int col = nt * 16 + rA;
      if (row < N_NODES)
        ((short*)hout)[(size_t)row * DIM + col] = f2bf(fmaxf(acc[nt][j], 0.f));
    }
}

// ---------- scoring (bf16 h) ----------
__global__ void k_score(const unsigned* __restrict__ h, const int* __restrict__ heads,
                        const int* __restrict__ rels, const int* __restrict__ tails,
                        const float* __restrict__ rel_emb, const float* __restrict__ path_feat,
                        const int* __restrict__ task_idx, const float* __restrict__ delta_w,
                        const float* __restrict__ lambda_logit, const float* __restrict__ rule_init,
                        float* __restrict__ out) {
  int q = (blockIdx.x * 256 + threadIdx.x) >> 6;
  int lane = threadIdx.x & 63;
  int hd = heads[q], tl = tails[q], rl = rels[q];
  unsigned ua = h[(size_t)hd * 64 + lane];
  unsigned uc = h[(size_t)tl * 64 + lane];
  float2 r = *(const float2*)(rel_emb + (size_t)rl * DIM + lane * 2);
  float s = bf_lo(ua) * r.x * bf_lo(uc) + bf_hi(ua) * r.y * bf_hi(uc);
  #pragma unroll
  for (int off = 32; off; off >>= 1) s += __shfl_xor(s, off, 64);
  if (lane == 0) {
    int task = task_idx[0];
    float sp = 0.f;
    #pragma unroll
    for (int p = 0; p < PATH_DIM; p++)
      sp += path_feat[q * PATH_DIM + p] *
            (rule_init[task * PATH_DIM + p] + delta_w[task * PATH_DIM + p]);
    float lam = 1.f / (1.f + __expf(-lambda_logit[task]));
    out[q] = lam * s + (1.f - lam) * sp;
  }
}

extern "C" void kernel_launch(void* const* d_in, const int* in_sizes, int n_in,
                              void* d_out, int out_size, void* d_ws, size_t ws_size,
                              hipStream_t stream) {
  const int*   node_ids   = (const int*)d_in[0];
  const int*   edge_index = (const int*)d_in[1];
  const int*   edge_type  = (const int*)d_in[2];
  const int*   heads      = (const int*)d_in[3];
  const int*   rels       = (const int*)d_in[4];
  const int*   tails      = (const int*)d_in[5];
  const float* path_feat  = (const float*)d_in[6];
  const int*   task_idx   = (const int*)d_in[7];
  const float* entity_emb = (const float*)d_in[8];
  const float* rel_emb    = (const float*)d_in[9];
  const float* W_self     = (const float*)d_in[10];
  const float* W_rel      = (const float*)d_in[11];
  const float* delta_w    = (const float*)d_in[12];
  const float* lambda_lg  = (const float*)d_in[13];
  const float* rule_init  = (const float*)d_in[14];

  char* ws = (char*)d_ws;
  size_t off = 0;
  auto alloc = [&](size_t bytes) -> void* {
    void* p = ws + off;
    off = (off + bytes + 255) & ~(size_t)255;
    return p;
  };
  unsigned* h_a    = (unsigned*)alloc((size_t)N_NODES * DIM * 2);
  unsigned* h_b    = (unsigned*)alloc((size_t)N_NODES * DIM * 2);
  short*    wt     = (short*)alloc((size_t)2 * NG * 8 * 512 * 2);
  int*      offs   = (int*)alloc((size_t)(NK + 1) * 4);
  int*      ssrc   = (int*)alloc((size_t)E_EDGES * 4);
  int*      hist   = (int*)alloc((size_t)(NK + 1) * 4);
  int*      cursor = (int*)alloc((size_t)NK * 4);
  int*      bsum   = (int*)alloc((size_t)NBLK_SEG * 4);

  hipMemsetAsync(hist, 0, (size_t)(NK + 1) * 4, stream);
  k_prep<<<EB + H0B + WCB, 256, 0, stream>>>(edge_index, edge_type, hist,
                                             node_ids, entity_emb, h_a,
                                             W_rel, W_self, wt);
  k_bsum<<<NBLK_SEG, 256, 0, stream>>>(hist, bsum);
  k_bscan<<<1, 1024, 0, stream>>>(bsum);
  k_offsets<<<NBLK_SEG, 256, 0, stream>>>(hist, bsum, offs, cursor);
  k_scatter<<<EB, 256, 0, stream>>>(edge_index, edge_type, cursor, ssrc);

  const unsigned* hin = h_a;
  unsigned* hout = h_b;
  int nblk = (N_NODES + BM - 1) / BM;
  for (int l = 0; l < 2; l++) {
    k_layer<<<nblk, 256, 0, stream>>>(hin, offs, ssrc,
                                      wt + (size_t)l * NG * 8 * 512, hout);
    const unsigned* tmp = hout;
    hout = (unsigned*)hin;
    hin = tmp;
  }
  k_score<<<NQ / 4, 256, 0, stream>>>(hin, heads, rels, tails, rel_emb, path_feat,
                                      task_idx, delta_w, lambda_lg, rule_init,
                                      (float*)d_out);
}

// Round 13
// 552.384 us; speedup vs baseline: 1.3616x; 1.3616x over previous
//
#include <hip/hip_runtime.h>

#define N_NODES 50000
#define N_ENT   100000
#define N_REL   16
#define DIM     128
#define E_EDGES 600000
#define NQ      8192
#define PATH_DIM 5
#define NK      (N_NODES * N_REL)        /* 800000 (rel,dst) segments, rel-major */
#define NBLK_SEG (NK / 256)              /* 3125 */
#define KTOT    (N_REL * DIM + DIM)      /* 2176 */
#define NG      (KTOT / 32)              /* 68 */
#define BM      64                       /* rows per block (4 waves x 16) */
#define TMAX    16                       /* staged edges per wave-relation */
#define EB      ((E_EDGES + 255) / 256)
#define H0B     ((N_NODES * 32) / 256)
#define WCB     ((2 * NG * 8 * 512) / 256)

typedef __attribute__((ext_vector_type(8))) short short8;
typedef __attribute__((ext_vector_type(4))) float floatx4;
typedef __attribute__((ext_vector_type(4))) unsigned uintx4;

static __device__ __forceinline__ short f2bf(float x) {
  unsigned u = __builtin_bit_cast(unsigned, x);
  u = (u + 0x7FFFu + ((u >> 16) & 1u)) >> 16;   // RNE
  return (short)u;
}
static __device__ __forceinline__ float bf_lo(unsigned u) {
  return __builtin_bit_cast(float, u << 16);
}
static __device__ __forceinline__ float bf_hi(unsigned u) {
  return __builtin_bit_cast(float, u & 0xffff0000u);
}
static __device__ __forceinline__ unsigned pk2(float a, float b) {
  return (unsigned)(unsigned short)f2bf(a) | ((unsigned)(unsigned short)f2bf(b) << 16);
}

static __device__ __forceinline__ int wave_incl_scan(int x) {
  int lane = threadIdx.x & 63;
  #pragma unroll
  for (int off = 1; off < 64; off <<= 1) {
    int y = __shfl_up(x, off, 64);
    if (lane >= off) x += y;
  }
  return x;
}

// global->LDS direct stage (mechanism verified in round 10):
// per-lane global source; uniform LDS base, HW writes lane i at base + i*4.
#define GLOAD_LDS4(g, l) __builtin_amdgcn_global_load_lds(                     \
    (const __attribute__((address_space(1))) void*)(g),                        \
    (__attribute__((address_space(3))) void*)(l), 4, 0, 0)
#define SB() __builtin_amdgcn_sched_barrier(0)
#define WAIT_VM0() do { asm volatile("s_waitcnt vmcnt(0)" ::: "memory"); SB(); } while (0)

// ---------- fused prep: edge hist | h0 gather | weight tiles ----------
__global__ void k_prep(const int* __restrict__ ei, const int* __restrict__ et,
                       int* __restrict__ hist,
                       const int* __restrict__ nid, const float* __restrict__ emb,
                       unsigned* __restrict__ h,
                       const float* __restrict__ wrel, const float* __restrict__ wself,
                       short* __restrict__ wt) {
  int b = blockIdx.x, t = threadIdx.x;
  if (b < EB) {
    int e = b * 256 + t;
    if (e < E_EDGES) {
      int key = et[e] * N_NODES + ei[E_EDGES + e];
      atomicAdd(&hist[key], 1);
    }
  } else if (b < EB + H0B) {
    int g = (b - EB) * 256 + t;                    // over N*32
    int n = g >> 5, q = g & 31;
    float4 v = *(const float4*)(emb + (size_t)nid[n] * DIM + q * 4);
    uint2 pk;
    pk.x = pk2(v.x, v.y);
    pk.y = pk2(v.z, v.w);
    *(uint2*)(h + (size_t)n * 64 + q * 2) = pk;
  } else {
    // wt layout: [l][g=k/32][nt8=n/16] tile [16 rA][32 q] shorts (1KB)
    int idx = (b - EB - H0B) * 256 + t;
    int within = idx & 511;
    int tile = idx >> 9;
    int rA = within >> 5, q = within & 31;
    int nt8 = tile & 7;
    int lg = tile >> 3;
    int l = lg / NG, g = lg % NG;
    int n = nt8 * 16 + rA;
    int k = g * 32 + q;
    float v;
    if (k < N_REL * DIM) {
      int r = k >> 7, d = k & 127;
      v = wrel[(((size_t)l * N_REL + r) * DIM + d) * DIM + n];
    } else {
      int d = k - N_REL * DIM;
      v = wself[((size_t)l * DIM + d) * DIM + n];
    }
    wt[idx] = f2bf(v);
  }
}

__global__ void k_bsum(const int* __restrict__ hist, int* __restrict__ bsum) {
  int t = threadIdx.x;
  int v = hist[blockIdx.x * 256 + t];
  #pragma unroll
  for (int off = 32; off; off >>= 1) v += __shfl_xor(v, off, 64);
  __shared__ int s4[4];
  if ((t & 63) == 0) s4[t >> 6] = v;
  __syncthreads();
  if (t == 0) bsum[blockIdx.x] = s4[0] + s4[1] + s4[2] + s4[3];
}

// k_offsets now computes its own block prefix over bsum (kills k_bscan launch):
// 3125 L2-hot ints, <=13 reads/thread.
__global__ void k_offsets(const int* __restrict__ hist, const int* __restrict__ bsum,
                          int* __restrict__ offs, int* __restrict__ cursor) {
  int t = threadIdx.x;
  int b = blockIdx.x;
  int g = b * 256 + t;
  int part = 0;
  for (int i = t; i < b; i += 256) part += bsum[i];
  #pragma unroll
  for (int off = 32; off; off >>= 1) part += __shfl_xor(part, off, 64);
  __shared__ int pre4[4];
  int wid = t >> 6, lane = t & 63;
  if (lane == 0) pre4[wid] = part;
  __syncthreads();
  int blockpre = pre4[0] + pre4[1] + pre4[2] + pre4[3];

  int v = hist[g];
  int incl = wave_incl_scan(v);
  __shared__ int wsum[4];
  if (lane == 63) wsum[wid] = incl;
  __syncthreads();
  int wexcl = 0;
  for (int i = 0; i < wid; i++) wexcl += wsum[i];
  int off = blockpre + wexcl + incl - v;
  offs[g] = off;
  cursor[g] = off;
  if (g == NK - 1) offs[NK] = off + v;
}

__global__ void k_scatter(const int* __restrict__ ei, const int* __restrict__ et,
                          int* __restrict__ cursor, int* __restrict__ ssrc) {
  int e = blockIdx.x * 256 + threadIdx.x;
  if (e >= E_EDGES) return;
  int src = ei[e];
  int key = et[e] * N_NODES + ei[E_EDGES + e];
  int pos = atomicAdd(&cursor[key], 1);
  ssrc[pos] = src;
}

// ---------- fused layer: wave-private LDS staging, zero K-loop barriers ----------
// Wave owns 16 rows; lane=(segment rA, chans quad*8+ks*32..+7). Per relation:
// 16 fixed global_load_lds stage the wave's edge rows (double-buffered, wave-
// private -> per-wave vmcnt is the only sync). Phase top: vmcnt(0) drains loads
// issued one full phase earlier (latency hidden under accum+MFMA). 16B-chunk
// XOR swizzle (source+read, rule both-sides) kills the 16-way ds_read conflict.
__global__ __launch_bounds__(256, 4)
void k_layer(const unsigned* __restrict__ hin, const int* __restrict__ offs,
             const int* __restrict__ ssrc, const short* __restrict__ wt,
             unsigned* __restrict__ hout) {
  __shared__ int offsS[16][66];                 // 4.2 KB
  __shared__ unsigned ebuf[4][2][TMAX][64];     // 32 KB staged edge rows
  int t = threadIdx.x;
  int w = t >> 6, lane = t & 63;
  int quad = lane >> 4, rA = lane & 15;
  int w16 = w * 16;
  int row0 = blockIdx.x * BM;

  for (int idx = t; idx < 16 * 80; idx += 256) {
    int r = idx / 80, j = idx - r * 80;
    if (j < 65) offsS[r][j] = offs[min(r * N_NODES + row0 + j, NK)];
  }
  __syncthreads();                              // the only block barrier

  floatx4 acc[8];
  #pragma unroll
  for (int nt = 0; nt < 8; ++nt) acc[nt] = (floatx4)0.f;

  const short* hb = (const short*)hin;

  auto load_idv = [&](int r) -> int {           // coalesced wave load of edge ids
    int o0w = offsS[r][w16];
    return ssrc[min(o0w + lane, E_EDGES - 1)];
  };
  auto stage = [&](int buf, int idv) {          // 16 fixed gload_lds (256B rows)
    #pragma unroll
    for (int e = 0; e < TMAX; ++e) {
      int sid = __builtin_amdgcn_readlane(idv, e);      // literal lane index
      // source swizzle: LDS chunk (lane>>2) receives global chunk (lane>>2)^e
      unsigned voff = ((((unsigned)(lane >> 2) ^ (unsigned)e) << 4) |
                       (((unsigned)lane & 3u) << 2));
      GLOAD_LDS4((const char*)(hin + (size_t)sid * 64) + voff,
                 &ebuf[w][buf][e][0]);
    }
  };
  auto accum_mfma = [&](int r, int buf, int idv) {
    int o = offsS[r][w16 + rA];
    int c = offsS[r][w16 + rA + 1] - o;         // lane's segment count
    int o0w = offsS[r][w16];
    int tot = offsS[r][w16 + 16] - o0w;         // wave-uniform
    int base = o - o0w;
    float s[4][8];
    #pragma unroll
    for (int ks = 0; ks < 4; ++ks)
      #pragma unroll
      for (int m = 0; m < 8; ++m) s[ks][m] = 0.f;
    // staged part: positions [base, min(base+c, TMAX)) -- divergent loop, LDS reads
    int pend = min(base + c, TMAX);
    for (int p = base; p < pend; ++p) {
      const unsigned* rowp = &ebuf[w][buf][0][0] + p * 64;
      #pragma unroll
      for (int ks = 0; ks < 4; ++ks) {
        int ch = ks * 4 + quad;
        uint4 d = *(const uint4*)(rowp + (((unsigned)ch ^ (unsigned)(p & 15)) << 2));
        s[ks][0] += bf_lo(d.x); s[ks][1] += bf_hi(d.x);
        s[ks][2] += bf_lo(d.y); s[ks][3] += bf_hi(d.y);
        s[ks][4] += bf_lo(d.z); s[ks][5] += bf_hi(d.z);
        s[ks][6] += bf_lo(d.w); s[ks][7] += bf_hi(d.w);
      }
    }
    if (tot > TMAX) {                           // wave-uniform overflow (~10% phases)
      for (int p = TMAX; p < tot; ++p) {        // uniform p: all lanes active
        int sid = (p < 64) ? __shfl(idv, p, 64) : ssrc[o0w + p];
        if (p >= base && p < base + c) {        // per-lane membership
          const short* hp = hb + (size_t)sid * DIM + quad * 8;
          #pragma unroll
          for (int ks = 0; ks < 4; ++ks) {
            uint4 d = *(const uint4*)(hp + ks * 32);
            s[ks][0] += bf_lo(d.x); s[ks][1] += bf_hi(d.x);
            s[ks][2] += bf_lo(d.y); s[ks][3] += bf_hi(d.y);
            s[ks][4] += bf_lo(d.z); s[ks][5] += bf_hi(d.z);
            s[ks][6] += bf_lo(d.w); s[ks][7] += bf_hi(d.w);
          }
        }
      }
    }
    float inv = 1.0f / (float)(c > 0 ? c : 1);  // lane-local
    #pragma unroll
    for (int ks = 0; ks < 4; ++ks) {
      uintx4 ap;
      #pragma unroll
      for (int m = 0; m < 4; ++m) {
        float a = s[ks][2 * m] * inv, b = s[ks][2 * m + 1] * inv;
        unsigned pk;
        asm("v_cvt_pk_bf16_f32 %0, %1, %2" : "=v"(pk) : "v"(a), "v"(b));  // RNE
        ap[m] = pk;
      }
      short8 af = __builtin_bit_cast(short8, ap);
      const short* bp = wt + (size_t)((r * 4 + ks) * 8) * 512 + rA * 32 + quad * 8;
      #pragma unroll
      for (int nt = 0; nt < 8; ++nt) {
        short8 b = *(const short8*)(bp + nt * 512);   // 1KB tile, L2-hot
        acc[nt] = __builtin_amdgcn_mfma_f32_16x16x32_bf16(af, b, acc[nt], 0, 0, 0);
      }
    }
  };

  // ---- prologue: ids for rels 0,1; stage rel 0; ids for rel 2 ----
  int idv0 = load_idv(0);
  int idv1 = load_idv(1);
  WAIT_VM0();
  stage(0, idv0);
  int idv2 = load_idv(2);
  int buf = 0;

  // ---- main loop: rels 0..14 (stage r+1 overlaps accum+MFMA of r) ----
  for (int r = 0; r < 15; ++r) {
    WAIT_VM0();                     // stage(r) + idv(r+2) landed (issued a phase ago)
    stage(buf ^ 1, idv1);           // stage r+1
    int idvn = load_idv(min(r + 3, 15));
    SB();                           // pin issues above the accum
    accum_mfma(r, buf, idv0);
    idv0 = idv1; idv1 = idv2; idv2 = idvn;
    buf ^= 1;
  }

  // ---- rel 15 ----
  WAIT_VM0();
  accum_mfma(15, buf, idv0);

  // ---- self slot: A-frag = raw bf16 slices of own h row ----
  {
    int lr = min(row0 + w16 + rA, N_NODES - 1);
    const short* hp = hb + (size_t)lr * DIM + quad * 8;
    #pragma unroll
    for (int ks = 0; ks < 4; ++ks) {
      short8 af = *(const short8*)(hp + ks * 32);
      const short* bp = wt + (size_t)((16 * 4 + ks) * 8) * 512 + rA * 32 + quad * 8;
      #pragma unroll
      for (int nt = 0; nt < 8; ++nt) {
        short8 b = *(const short8*)(bp + nt * 512);
        acc[nt] = __builtin_amdgcn_mfma_f32_16x16x32_bf16(af, b, acc[nt], 0, 0, 0);
      }
    }
  }

  // epilogue: C row=quad*4+j, col=nt*16+rA
  #pragma unroll
  for (int nt = 0; nt < 8; ++nt)
    #pragma unroll
    for (int j = 0; j < 4; ++j) {
      int row = row0 + w16 + quad * 4 + j;
      int col = nt * 16 + rA;
      if (row < N_NODES)
        ((short*)hout)[(size_t)row * DIM + col] = f2bf(fmaxf(acc[nt][j], 0.f));
    }
}

// ---------- scoring (bf16 h) ----------
__global__ void k_score(const unsigned* __restrict__ h, const int* __restrict__ heads,
                        const int* __restrict__ rels, const int* __restrict__ tails,
                        const float* __restrict__ rel_emb, const float* __restrict__ path_feat,
                        const int* __restrict__ task_idx, const float* __restrict__ delta_w,
                        const float* __restrict__ lambda_logit, const float* __restrict__ rule_init,
                        float* __restrict__ out) {
  int q = (blockIdx.x * 256 + threadIdx.x) >> 6;
  int lane = threadIdx.x & 63;
  int hd = heads[q], tl = tails[q], rl = rels[q];
  unsigned ua = h[(size_t)hd * 64 + lane];
  unsigned uc = h[(size_t)tl * 64 + lane];
  float2 r = *(const float2*)(rel_emb + (size_t)rl * DIM + lane * 2);
  float s = bf_lo(ua) * r.x * bf_lo(uc) + bf_hi(ua) * r.y * bf_hi(uc);
  #pragma unroll
  for (int off = 32; off; off >>= 1) s += __shfl_xor(s, off, 64);
  if (lane == 0) {
    int task = task_idx[0];
    float sp = 0.f;
    #pragma unroll
    for (int p = 0; p < PATH_DIM; p++)
      sp += path_feat[q * PATH_DIM + p] *
            (rule_init[task * PATH_DIM + p] + delta_w[task * PATH_DIM + p]);
    float lam = 1.f / (1.f + __expf(-lambda_logit[task]));
    out[q] = lam * s + (1.f - lam) * sp;
  }
}

extern "C" void kernel_launch(void* const* d_in, const int* in_sizes, int n_in,
                              void* d_out, int out_size, void* d_ws, size_t ws_size,
                              hipStream_t stream) {
  const int*   node_ids   = (const int*)d_in[0];
  const int*   edge_index = (const int*)d_in[1];
  const int*   edge_type  = (const int*)d_in[2];
  const int*   heads      = (const int*)d_in[3];
  const int*   rels       = (const int*)d_in[4];
  const int*   tails      = (const int*)d_in[5];
  const float* path_feat  = (const float*)d_in[6];
  const int*   task_idx   = (const int*)d_in[7];
  const float* entity_emb = (const float*)d_in[8];
  const float* rel_emb    = (const float*)d_in[9];
  const float* W_self     = (const float*)d_in[10];
  const float* W_rel      = (const float*)d_in[11];
  const float* delta_w    = (const float*)d_in[12];
  const float* lambda_lg  = (const float*)d_in[13];
  const float* rule_init  = (const float*)d_in[14];

  char* ws = (char*)d_ws;
  size_t off = 0;
  auto alloc = [&](size_t bytes) -> void* {
    void* p = ws + off;
    off = (off + bytes + 255) & ~(size_t)255;
    return p;
  };
  unsigned* h_a    = (unsigned*)alloc((size_t)N_NODES * DIM * 2);
  unsigned* h_b    = (unsigned*)alloc((size_t)N_NODES * DIM * 2);
  short*    wt     = (short*)alloc((size_t)2 * NG * 8 * 512 * 2);
  int*      offs   = (int*)alloc((size_t)(NK + 1) * 4);
  int*      ssrc   = (int*)alloc((size_t)E_EDGES * 4);
  int*      hist   = (int*)alloc((size_t)(NK + 1) * 4);
  int*      cursor = (int*)alloc((size_t)NK * 4);
  int*      bsum   = (int*)alloc((size_t)NBLK_SEG * 4);

  hipMemsetAsync(hist, 0, (size_t)(NK + 1) * 4, stream);
  k_prep<<<EB + H0B + WCB, 256, 0, stream>>>(edge_index, edge_type, hist,
                                             node_ids, entity_emb, h_a,
                                             W_rel, W_self, wt);
  k_bsum<<<NBLK_SEG, 256, 0, stream>>>(hist, bsum);
  k_offsets<<<NBLK_SEG, 256, 0, stream>>>(hist, bsum, offs, cursor);
  k_scatter<<<EB, 256, 0, stream>>>(edge_index, edge_type, cursor, ssrc);

  const unsigned* hin = h_a;
  unsigned* hout = h_b;
  int nblk = (N_NODES + BM - 1) / BM;
  for (int l = 0; l < 2; l++) {
    k_layer<<<nblk, 256, 0, stream>>>(hin, offs, ssrc,
                                      wt + (size_t)l * NG * 8 * 512, hout);
    const unsigned* tmp = hout;
    hout = (unsigned*)hin;
    hin = tmp;
  }
  k_score<<<NQ / 4, 256, 0, stream>>>(hin, heads, rels, tails, rel_emb, path_feat,
                                      task_idx, delta_w, lambda_lg, rule_init,
                                      (float*)d_out);
}

// Round 14
// 497.232 us; speedup vs baseline: 1.5126x; 1.1109x over previous
//
#include <hip/hip_runtime.h>

#define N_NODES 50000
#define N_ENT   100000
#define N_REL   16
#define DIM     128
#define E_EDGES 600000
#define NQ      8192
#define PATH_DIM 5
#define NK      (N_NODES * N_REL)        /* 800000 (rel,dst) segments, rel-major */
#define NBLK_SEG (NK / 256)              /* 3125 */
#define KTOT    (N_REL * DIM + DIM)      /* 2176 */
#define NG      (KTOT / 32)              /* 68 */
#define BM      32                       /* rows per block (2 row-groups x 16) */
#define EB      ((E_EDGES + 255) / 256)
#define H0B     ((N_NODES * 32) / 256)
#define WCB     ((2 * NG * 8 * 512) / 256)

typedef __attribute__((ext_vector_type(8))) short short8;
typedef __attribute__((ext_vector_type(4))) float floatx4;
typedef __attribute__((ext_vector_type(4))) unsigned uintx4;

static __device__ __forceinline__ short f2bf(float x) {
  unsigned u = __builtin_bit_cast(unsigned, x);
  u = (u + 0x7FFFu + ((u >> 16) & 1u)) >> 16;   // RNE
  return (short)u;
}
static __device__ __forceinline__ float bf_lo(unsigned u) {
  return __builtin_bit_cast(float, u << 16);
}
static __device__ __forceinline__ float bf_hi(unsigned u) {
  return __builtin_bit_cast(float, u & 0xffff0000u);
}
static __device__ __forceinline__ unsigned pk2(float a, float b) {
  return (unsigned)(unsigned short)f2bf(a) | ((unsigned)(unsigned short)f2bf(b) << 16);
}

static __device__ __forceinline__ int wave_incl_scan(int x) {
  int lane = threadIdx.x & 63;
  #pragma unroll
  for (int off = 1; off < 64; off <<= 1) {
    int y = __shfl_up(x, off, 64);
    if (lane >= off) x += y;
  }
  return x;
}

// ---------- fused prep: edge hist | h0 gather | weight tiles ----------
__global__ void k_prep(const int* __restrict__ ei, const int* __restrict__ et,
                       int* __restrict__ hist,
                       const int* __restrict__ nid, const float* __restrict__ emb,
                       unsigned* __restrict__ h,
                       const float* __restrict__ wrel, const float* __restrict__ wself,
                       short* __restrict__ wt) {
  int b = blockIdx.x, t = threadIdx.x;
  if (b < EB) {
    int e = b * 256 + t;
    if (e < E_EDGES) {
      int key = et[e] * N_NODES + ei[E_EDGES + e];
      atomicAdd(&hist[key], 1);
    }
  } else if (b < EB + H0B) {
    int g = (b - EB) * 256 + t;                    // over N*32
    int n = g >> 5, q = g & 31;
    float4 v = *(const float4*)(emb + (size_t)nid[n] * DIM + q * 4);
    uint2 pk;
    pk.x = pk2(v.x, v.y);
    pk.y = pk2(v.z, v.w);
    *(uint2*)(h + (size_t)n * 64 + q * 2) = pk;
  } else {
    // wt layout: [l][g=k/32][nt8=n/16] tile [16 rA][32 q] shorts (1KB).
    // Lane varies rA (=n) fastest -> coalesced wrel/wself reads (was 64-way scatter).
    int idx = (b - EB - H0B) * 256 + t;
    int u = idx & 511;
    int tile = idx >> 9;
    int rA = u & 15, q = u >> 4;
    int nt8 = tile & 7;
    int lg = tile >> 3;
    int l = lg / NG, g = lg % NG;
    int n = nt8 * 16 + rA;
    int k = g * 32 + q;
    float v;
    if (k < N_REL * DIM) {
      int r = k >> 7, d = k & 127;
      v = wrel[(((size_t)l * N_REL + r) * DIM + d) * DIM + n];
    } else {
      int d = k - N_REL * DIM;
      v = wself[((size_t)l * DIM + d) * DIM + n];
    }
    wt[(size_t)tile * 512 + rA * 32 + q] = f2bf(v);
  }
}

__global__ void k_bsum(const int* __restrict__ hist, int* __restrict__ bsum) {
  int t = threadIdx.x;
  int v = hist[blockIdx.x * 256 + t];
  #pragma unroll
  for (int off = 32; off; off >>= 1) v += __shfl_xor(v, off, 64);
  __shared__ int s4[4];
  if ((t & 63) == 0) s4[t >> 6] = v;
  __syncthreads();
  if (t == 0) bsum[blockIdx.x] = s4[0] + s4[1] + s4[2] + s4[3];
}

// k_offsets computes its own block prefix over bsum (no separate scan kernel)
__global__ void k_offsets(const int* __restrict__ hist, const int* __restrict__ bsum,
                          int* __restrict__ offs, int* __restrict__ cursor) {
  int t = threadIdx.x;
  int b = blockIdx.x;
  int g = b * 256 + t;
  int part = 0;
  for (int i = t; i < b; i += 256) part += bsum[i];
  #pragma unroll
  for (int off = 32; off; off >>= 1) part += __shfl_xor(part, off, 64);
  __shared__ int pre4[4];
  int wid = t >> 6, lane = t & 63;
  if (lane == 0) pre4[wid] = part;
  __syncthreads();
  int blockpre = pre4[0] + pre4[1] + pre4[2] + pre4[3];

  int v = hist[g];
  int incl = wave_incl_scan(v);
  __shared__ int wsum[4];
  if (lane == 63) wsum[wid] = incl;
  __syncthreads();
  int wexcl = 0;
  for (int i = 0; i < wid; i++) wexcl += wsum[i];
  int off = blockpre + wexcl + incl - v;
  offs[g] = off;
  cursor[g] = off;
  if (g == NK - 1) offs[NK] = off + v;
}

__global__ void k_scatter(const int* __restrict__ ei, const int* __restrict__ et,
                          int* __restrict__ cursor, int* __restrict__ ssrc) {
  int e = blockIdx.x * 256 + threadIdx.x;
  if (e >= E_EDGES) return;
  int src = ei[e];
  int key = et[e] * N_NODES + ei[E_EDGES + e];
  int pos = atomicAdd(&cursor[key], 1);
  ssrc[pos] = src;
}

// ---------- fused layer: per-lane segments + K-split waves (2x occupancy) ----------
// 4 waves = 2 row-groups x 2 K-groups. kg0: rels 0-7; kg1: rels 8-15 + self.
// Inner loop is round-11's verified per-lane gather (lane=(segment rA, chans
// quad*8+ks*32..+7)); partials combined through LDS with ONE barrier.
__global__ __launch_bounds__(256, 4)
void k_layer(const unsigned* __restrict__ hin, const int* __restrict__ offs,
             const int* __restrict__ ssrc, const short* __restrict__ wt,
             unsigned* __restrict__ hout) {
  __shared__ int offsS[16][40];        // 16 rels x 33 boundaries (rows row0..row0+32)
  __shared__ float cred[2][32][64];    // [rg][nt*4+j][lane] f32 partials, 16 KB
  int t = threadIdx.x;
  int w = t >> 6, lane = t & 63;
  int quad = lane >> 4, rA = lane & 15;
  int rg = w >> 1, kg = w & 1;
  int row0 = blockIdx.x * BM;
  int rbase = row0 + rg * 16;
  int rg16 = rg * 16;

  for (int idx = t; idx < 16 * 40; idx += 256) {
    int r = idx / 40, j = idx - r * 40;
    if (j < 33) offsS[r][j] = offs[min(r * N_NODES + row0 + j, NK)];
  }
  __syncthreads();

  floatx4 acc[8];
  #pragma unroll
  for (int nt = 0; nt < 8; ++nt) acc[nt] = (floatx4)0.f;

  const short* hb = (const short*)hin;

  int rlo = kg * 8, rhi = rlo + 8;
  for (int r = rlo; r < rhi; ++r) {
    int o = offsS[r][rg16 + rA];
    int c = offsS[r][rg16 + rA + 1] - o;    // lane-local count
    int mc = c;
    #pragma unroll
    for (int sh = 32; sh; sh >>= 1) mc = max(mc, __shfl_xor(mc, sh, 64));
    float s[4][8];
    #pragma unroll
    for (int ks = 0; ks < 4; ++ks)
      #pragma unroll
      for (int m = 0; m < 8; ++m) s[ks][m] = 0.f;
    int eid = (c > 0) ? ssrc[o] : 0;        // 4 quad-lanes share addr (broadcast)
    for (int i = 0; i < mc; ++i) {          // wave-uniform trip count
      int eidn = (i + 1 < c) ? ssrc[o + i + 1] : 0;   // prefetch next id
      if (i < c) {
        const short* hp = hb + (size_t)eid * DIM + quad * 8;
        #pragma unroll
        for (int ks = 0; ks < 4; ++ks) {    // 4 x 16B; quads cover 256B row
          uint4 d = *(const uint4*)(hp + ks * 32);
          s[ks][0] += bf_lo(d.x); s[ks][1] += bf_hi(d.x);
          s[ks][2] += bf_lo(d.y); s[ks][3] += bf_hi(d.y);
          s[ks][4] += bf_lo(d.z); s[ks][5] += bf_hi(d.z);
          s[ks][6] += bf_lo(d.w); s[ks][7] += bf_hi(d.w);
        }
      }
      eid = eidn;
    }
    float inv = 1.0f / (float)(c > 0 ? c : 1);  // lane-local, no readlane
    #pragma unroll
    for (int ks = 0; ks < 4; ++ks) {
      uintx4 ap;
      #pragma unroll
      for (int m = 0; m < 4; ++m) {
        float a = s[ks][2 * m] * inv, b = s[ks][2 * m + 1] * inv;
        unsigned pk;
        asm("v_cvt_pk_bf16_f32 %0, %1, %2" : "=v"(pk) : "v"(a), "v"(b));  // RNE
        ap[m] = pk;
      }
      short8 af = __builtin_bit_cast(short8, ap);
      const short* bp = wt + (size_t)((r * 4 + ks) * 8) * 512 + rA * 32 + quad * 8;
      #pragma unroll
      for (int nt = 0; nt < 8; ++nt) {
        short8 b = *(const short8*)(bp + nt * 512);   // 1KB tile, L2-hot
        acc[nt] = __builtin_amdgcn_mfma_f32_16x16x32_bf16(af, b, acc[nt], 0, 0, 0);
      }
    }
  }

  if (kg == 1) {
    // self slot: A-frag = raw bf16 slices of own h row
    int lr = min(rbase + rA, N_NODES - 1);
    const short* hp = hb + (size_t)lr * DIM + quad * 8;
    #pragma unroll
    for (int ks = 0; ks < 4; ++ks) {
      short8 af = *(const short8*)(hp + ks * 32);
      const short* bp = wt + (size_t)((16 * 4 + ks) * 8) * 512 + rA * 32 + quad * 8;
      #pragma unroll
      for (int nt = 0; nt < 8; ++nt) {
        short8 b = *(const short8*)(bp + nt * 512);
        acc[nt] = __builtin_amdgcn_mfma_f32_16x16x32_bf16(af, b, acc[nt], 0, 0, 0);
      }
    }
    // dump f32 partials (conflict-free: bank = lane%32)
    #pragma unroll
    for (int nt = 0; nt < 8; ++nt)
      #pragma unroll
      for (int j = 0; j < 4; ++j)
        cred[rg][nt * 4 + j][lane] = acc[nt][j];
  }
  __syncthreads();
  if (kg == 0) {
    // combine + relu + store.  C layout: row=quad*4+j, col=nt*16+rA
    #pragma unroll
    for (int nt = 0; nt < 8; ++nt)
      #pragma unroll
      for (int j = 0; j < 4; ++j) {
        float v = acc[nt][j] + cred[rg][nt * 4 + j][lane];
        int row = rbase + quad * 4 + j;
        int col = nt * 16 + rA;
        if (row < N_NODES)
          ((short*)hout)[(size_t)row * DIM + col] = f2bf(fmaxf(v, 0.f));
      }
  }
}

// ---------- scoring (bf16 h) ----------
__global__ void k_score(const unsigned* __restrict__ h, const int* __restrict__ heads,
                        const int* __restrict__ rels, const int* __restrict__ tails,
                        const float* __restrict__ rel_emb, const float* __restrict__ path_feat,
                        const int* __restrict__ task_idx, const float* __restrict__ delta_w,
                        const float* __restrict__ lambda_logit, const float* __restrict__ rule_init,
                        float* __restrict__ out) {
  int q = (blockIdx.x * 256 + threadIdx.x) >> 6;
  int lane = threadIdx.x & 63;
  int hd = heads[q], tl = tails[q], rl = rels[q];
  unsigned ua = h[(size_t)hd * 64 + lane];
  unsigned uc = h[(size_t)tl * 64 + lane];
  float2 r = *(const float2*)(rel_emb + (size_t)rl * DIM + lane * 2);
  float s = bf_lo(ua) * r.x * bf_lo(uc) + bf_hi(ua) * r.y * bf_hi(uc);
  #pragma unroll
  for (int off = 32; off; off >>= 1) s += __shfl_xor(s, off, 64);
  if (lane == 0) {
    int task = task_idx[0];
    float sp = 0.f;
    #pragma unroll
    for (int p = 0; p < PATH_DIM; p++)
      sp += path_feat[q * PATH_DIM + p] *
            (rule_init[task * PATH_DIM + p] + delta_w[task * PATH_DIM + p]);
    float lam = 1.f / (1.f + __expf(-lambda_logit[task]));
    out[q] = lam * s + (1.f - lam) * sp;
  }
}

extern "C" void kernel_launch(void* const* d_in, const int* in_sizes, int n_in,
                              void* d_out, int out_size, void* d_ws, size_t ws_size,
                              hipStream_t stream) {
  const int*   node_ids   = (const int*)d_in[0];
  const int*   edge_index = (const int*)d_in[1];
  const int*   edge_type  = (const int*)d_in[2];
  const int*   heads      = (const int*)d_in[3];
  const int*   rels       = (const int*)d_in[4];
  const int*   tails      = (const int*)d_in[5];
  const float* path_feat  = (const float*)d_in[6];
  const int*   task_idx   = (const int*)d_in[7];
  const float* entity_emb = (const float*)d_in[8];
  const float* rel_emb    = (const float*)d_in[9];
  const float* W_self     = (const float*)d_in[10];
  const float* W_rel      = (const float*)d_in[11];
  const float* delta_w    = (const float*)d_in[12];
  const float* lambda_lg  = (const float*)d_in[13];
  const float* rule_init  = (const float*)d_in[14];

  char* ws = (char*)d_ws;
  size_t off = 0;
  auto alloc = [&](size_t bytes) -> void* {
    void* p = ws + off;
    off = (off + bytes + 255) & ~(size_t)255;
    return p;
  };
  unsigned* h_a    = (unsigned*)alloc((size_t)N_NODES * DIM * 2);
  unsigned* h_b    = (unsigned*)alloc((size_t)N_NODES * DIM * 2);
  short*    wt     = (short*)alloc((size_t)2 * NG * 8 * 512 * 2);
  int*      offs   = (int*)alloc((size_t)(NK + 1) * 4);
  int*      ssrc   = (int*)alloc((size_t)E_EDGES * 4);
  int*      hist   = (int*)alloc((size_t)(NK + 1) * 4);
  int*      cursor = (int*)alloc((size_t)NK * 4);
  int*      bsum   = (int*)alloc((size_t)NBLK_SEG * 4);

  hipMemsetAsync(hist, 0, (size_t)(NK + 1) * 4, stream);
  k_prep<<<EB + H0B + WCB, 256, 0, stream>>>(edge_index, edge_type, hist,
                                             node_ids, entity_emb, h_a,
                                             W_rel, W_self, wt);
  k_bsum<<<NBLK_SEG, 256, 0, stream>>>(hist, bsum);
  k_offsets<<<NBLK_SEG, 256, 0, stream>>>(hist, bsum, offs, cursor);
  k_scatter<<<EB, 256, 0, stream>>>(edge_index, edge_type, cursor, ssrc);

  const unsigned* hin = h_a;
  unsigned* hout = h_b;
  int nblk = (N_NODES + BM - 1) / BM;
  for (int l = 0; l < 2; l++) {
    k_layer<<<nblk, 256, 0, stream>>>(hin, offs, ssrc,
                                      wt + (size_t)l * NG * 8 * 512, hout);
    const unsigned* tmp = hout;
    hout = (unsigned*)hin;
    hin = tmp;
  }
  k_score<<<NQ / 4, 256, 0, stream>>>(hin, heads, rels, tails, rel_emb, path_feat,
                                      task_idx, delta_w, lambda_lg, rule_init,
                                      (float*)d_out);
}